// Round 7
// baseline (520.156 us; speedup 1.0000x reference)
//
#include <hip/hip_runtime.h>

typedef __bf16 bf16;
typedef __bf16 bf16x8 __attribute__((ext_vector_type(8)));
typedef __bf16 bf16x4 __attribute__((ext_vector_type(4)));
typedef float f32x4 __attribute__((ext_vector_type(4)));

#define MFMA16(a, b, c) __builtin_amdgcn_mfma_f32_16x16x32_bf16(a, b, c, 0, 0, 0)

// Problem constants
#define Bq 2
#define Sq 2048
#define Eq 2048
#define Hq 16
#define Dq 128
#define N3E 6144

#define GLOAD_LDS16(gp, lp) \
  __builtin_amdgcn_global_load_lds( \
      (const __attribute__((address_space(1))) void*)(gp), \
      (__attribute__((address_space(3))) void*)(lp), 16, 0, 0)

__device__ __forceinline__ bf16 f2bf(float f) {
  unsigned u = __builtin_bit_cast(unsigned, f);
  u += 0x7FFFu + ((u >> 16) & 1u);
  unsigned short h = (unsigned short)(u >> 16);
  return __builtin_bit_cast(bf16, h);
}
__device__ __forceinline__ float bf2f(bf16 b) {
  unsigned short h = __builtin_bit_cast(unsigned short, b);
  return __builtin_bit_cast(float, (unsigned)h << 16);
}

// ---------------------------------------------------------------------------
// Kernel 0 (fused prep): one launch covering
//   blocks [0,4096)      : x fp32 -> xb bf16 (8 elems/thread)
//   blocks [4096,7168)   : W fp32 [k][n] -> wt bf16 [n][k] (64x64 transpose)
//   blocks [7168,7680)   : RoPE cos/sin table [Sq][64] float2
// ---------------------------------------------------------------------------
__global__ __launch_bounds__(256) void prep(const float* __restrict__ x,
                                            bf16* __restrict__ xb,
                                            const float* __restrict__ w,
                                            bf16* __restrict__ wt,
                                            float2* __restrict__ tbl) {
  __shared__ __align__(16) bf16 T[64][72];
  const int tid = threadIdx.x;
  const int bidx = blockIdx.x;

  if (bidx < 4096) {
    const size_t i = ((size_t)bidx * 256 + tid) * 8;
    float4 a = *(const float4*)(x + i);
    float4 b = *(const float4*)(x + i + 4);
    bf16x8 o;
    o[0] = f2bf(a.x); o[1] = f2bf(a.y); o[2] = f2bf(a.z); o[3] = f2bf(a.w);
    o[4] = f2bf(b.x); o[5] = f2bf(b.y); o[6] = f2bf(b.z); o[7] = f2bf(b.w);
    *(bf16x8*)(xb + i) = o;
  } else if (bidx < 4096 + 3072) {
    const int b2 = bidx - 4096;
    const int kb = b2 & 31;  // 2048/64
    const int nb = b2 >> 5;  // 6144/64
    const int k0 = kb * 64, n0 = nb * 64;
    {
      const int kr = tid >> 4, nc = (tid & 15) * 4;
#pragma unroll
      for (int p = 0; p < 4; ++p) {
        const int k = kr + p * 16;
        float4 v = *(const float4*)(w + (size_t)(k0 + k) * N3E + n0 + nc);
        T[nc + 0][k] = f2bf(v.x);
        T[nc + 1][k] = f2bf(v.y);
        T[nc + 2][k] = f2bf(v.z);
        T[nc + 3][k] = f2bf(v.w);
      }
    }
    __syncthreads();
#pragma unroll
    for (int q = 0; q < 2; ++q) {
      const int id = q * 256 + tid;
      const int n = id >> 3, ch = id & 7;
      bf16x8 v = *(const bf16x8*)&T[n][ch * 8];
      *(bf16x8*)(wt + (size_t)(n0 + n) * Eq + k0 + ch * 8) = v;
    }
  } else {
    const int i = (bidx - 7168) * 256 + tid;  // 0 .. Sq*64-1
    const int s = i >> 6, d = i & 63;
    const float freq = __expf(-(float)d * 0.14391157f);  // ln(10000)/64
    const float ang = (float)s * freq;
    float sv, cv;
    __sincosf(ang, &sv, &cv);
    tbl[i] = make_float2(cv, sv);
  }
}

// ---------------------------------------------------------------------------
// Kernel 1: qkv = xb @ wt^T. ROUND-1 STRUCTURE VERBATIM (proven 123-124 us
// across 4 measurements; MfmaUtil 35.7%, no spill): 128x256 tile, BK=64,
// ring-3 LDS (144 KiB), 512 threads = 8 waves (2Mx4N, 64x64/wave), single
// barrier per K-tile with COUNTED s_waitcnt vmcnt(6).
// ---------------------------------------------------------------------------
__global__ __launch_bounds__(512, 2) void gemm_qkv(
    const bf16* __restrict__ xb, const bf16* __restrict__ wt,
    const float2* __restrict__ tbl, bf16* __restrict__ qws,
    bf16* __restrict__ kws, bf16* __restrict__ vtws) {
  // 3 slots x (A 128x64 + B 256x64) bf16 = 3 * 24576 elems = 144 KiB
  __shared__ __align__(16) bf16 LDS[3 * 24576];

  const int tid = threadIdx.x;
  const int lane = tid & 63, wv = tid >> 6;
  const int q4 = lane >> 4, c = lane & 15;
  const int wm = (wv >> 2) * 64;   // wave M offset: 0 / 64
  const int wn = (wv & 3) * 64;    // wave N offset: 0 / 64 / 128 / 192
  const int cx = c & 7;            // read-side XOR key

  // XCD swizzle: 768 blocks % 8 == 0 -> 96 consecutive wg per XCD.
  const int bid = blockIdx.x;
  const int wg = (bid & 7) * 96 + (bid >> 3);
  const int m0 = (wg / 24) * 128;
  const int n0 = (wg % 24) * 256;

  f32x4 acc[4][4];
#pragma unroll
  for (int i = 0; i < 4; ++i)
#pragma unroll
    for (int j = 0; j < 4; ++j) acc[i][j] = {0.f, 0.f, 0.f, 0.f};

  const int NT = Eq / 64;  // 32 K-tiles

  auto stage = [&](int t, int st) {
    bf16* ab = LDS + st * 24576;
    bf16* bb = ab + 8192;
    const int k0 = t * 64;
#pragma unroll
    for (int it = 0; it < 2; ++it) {
      const int slot = it * 512 + tid;
      const int row = slot >> 3, kch = slot & 7;
      const int kcs = kch ^ (row & 7);  // source pre-swizzle (involution)
      GLOAD_LDS16(xb + (size_t)(m0 + row) * Eq + k0 + kcs * 8, ab + slot * 8);
    }
#pragma unroll
    for (int it = 0; it < 4; ++it) {
      const int slot = it * 512 + tid;
      const int row = slot >> 3, kch = slot & 7;
      const int kcs = kch ^ (row & 7);
      GLOAD_LDS16(wt + (size_t)(n0 + row) * Eq + k0 + kcs * 8, bb + slot * 8);
    }
  };

  // Prologue: tiles 0,1 in flight; wait only for tile 0 (6 newest = tile 1).
  stage(0, 0);
  stage(1, 1);
  asm volatile("s_waitcnt vmcnt(6)" ::: "memory");
  __builtin_amdgcn_s_barrier();

  int stC = 0;
#pragma unroll 1
  for (int t = 0; t < NT; ++t) {
    if (t + 2 < NT) {
      int ss = stC + 2;
      if (ss >= 3) ss -= 3;
      stage(t + 2, ss);  // slot (t+2)%3: not read by tiles t, t+1
    }
    const bf16* A = LDS + stC * 24576;
    const bf16* Bb = A + 8192;
#pragma unroll
    for (int kk = 0; kk < 64; kk += 32) {
      const int bch = kk >> 3;  // 0 or 4
      bf16x8 af[4], bfr[4];
#pragma unroll
      for (int i = 0; i < 4; ++i)
        af[i] = *(const bf16x8*)
            &A[(wm + i * 16 + c) * 64 + ((bch + q4) ^ cx) * 8];
#pragma unroll
      for (int j = 0; j < 4; ++j)
        bfr[j] = *(const bf16x8*)
            &Bb[(wn + j * 16 + c) * 64 + ((bch + q4) ^ cx) * 8];
      __builtin_amdgcn_s_setprio(1);
#pragma unroll
      for (int i = 0; i < 4; ++i)
#pragma unroll
        for (int j = 0; j < 4; ++j)
          acc[i][j] = MFMA16(af[i], bfr[j], acc[i][j]);
      __builtin_amdgcn_s_setprio(0);
    }
    if (t + 1 < NT) {
      // Counted: drains tile t+1's loads (oldest), keeps t+2's 6 in flight.
      if (t + 2 < NT) asm volatile("s_waitcnt vmcnt(6)" ::: "memory");
      else            asm volatile("s_waitcnt vmcnt(0)" ::: "memory");
      __builtin_amdgcn_s_barrier();
    }
    stC = stC == 2 ? 0 : stC + 1;
  }
  __syncthreads();  // full drain once; LDS reused below

  // ---- epilogue: per-head (2 heads per 256-wide N tile) ----
  const int t3 = n0 >> 11;         // 0=q, 1=k, 2=v
  const int b = m0 >> 11;
  const int s0 = m0 & 2047;
  const int h0 = (n0 & 2047) >> 7;

  bf16* E = LDS;  // reused: [128][136] bf16 = 34816 B

  if (t3 == 2) {
#pragma unroll 1
    for (int hh = 0; hh < 2; ++hh) {
      if (((wv & 3) >> 1) == hh) {  // waves owning this head's 128 cols
#pragma unroll
        for (int i = 0; i < 4; ++i)
#pragma unroll
          for (int j = 0; j < 4; ++j) {
            bf16x4 pv;
            pv[0] = f2bf(acc[i][j][0]); pv[1] = f2bf(acc[i][j][1]);
            pv[2] = f2bf(acc[i][j][2]); pv[3] = f2bf(acc[i][j][3]);
            *(bf16x4*)&E[((wn & 127) + j * 16 + c) * 136 + wm + i * 16 +
                         q4 * 4] = pv;
          }
      }
      __syncthreads();
      bf16* vbase = vtws + ((size_t)(b * Hq + h0 + hh) * Dq) * Sq + s0;
#pragma unroll
      for (int p = 0; p < 4; ++p) {
        const int id = p * 512 + tid;
        const int d = id >> 4, ch = id & 15;
        bf16x8 v = *(const bf16x8*)&E[d * 136 + ch * 8];
        *(bf16x8*)&vbase[(size_t)d * Sq + ch * 8] = v;
      }
      __syncthreads();
    }
  } else {
#pragma unroll 1
    for (int hh = 0; hh < 2; ++hh) {
      if (((wv & 3) >> 1) == hh) {
#pragma unroll
        for (int i = 0; i < 4; ++i)
#pragma unroll
          for (int j = 0; j < 4; ++j)
#pragma unroll
            for (int rr = 0; rr < 4; ++rr)
              E[(wm + i * 16 + q4 * 4 + rr) * 136 + (wn & 127) + j * 16 + c] =
                  f2bf(acc[i][j][rr]);
      }
      __syncthreads();
      bf16* hd = ((t3 == 0) ? qws : kws) +
                 ((size_t)(b * Hq + h0 + hh) * Sq + s0) * Dq;
#pragma unroll
      for (int p = 0; p < 2; ++p) {
        const int row = p * 64 + (tid >> 3);
        const int dlow = (tid & 7) * 8;
        const int s = s0 + row;
        bf16x8 lo = *(const bf16x8*)&E[row * 136 + dlow];
        bf16x8 hi = *(const bf16x8*)&E[row * 136 + 64 + dlow];
        const float2* tb = tbl + (size_t)s * 64 + dlow;
        bf16x8 olo, ohi;
#pragma unroll
        for (int e = 0; e < 8; ++e) {
          const float cv = tb[e].x, sv = tb[e].y;
          const float x1 = bf2f(lo[e]), x2 = bf2f(hi[e]);
          olo[e] = f2bf(x1 * cv - x2 * sv);
          ohi[e] = f2bf(x2 * cv + x1 * sv);
        }
        *(bf16x8*)&hd[(size_t)row * Dq + dlow] = olo;
        *(bf16x8*)&hd[(size_t)row * Dq + 64 + dlow] = ohi;
      }
      __syncthreads();
    }
  }
}

// ---------------------------------------------------------------------------
// Kernel 3: flash attention. Round-7 changes vs R6:
//  (1) T13 defer-max REVERTED (its __any gate over 16 q-rows ~never skips:
//      P(skip) ~ 1-16/kb; pure overhead) -> exact R2 softmax restored.
//  (2) V no longer staged in LDS: PV reads V fragments DIRECTLY from global
//      vtws [d][s] (16B/lane, L2/L3-resident: all KV = 32 MB < 256 MB L3).
//      V had no intra-block LDS reuse (streamed once per chunk) — per m169,
//      staging cache-resident streams is pure overhead. LDS 73.7->41.9 KB,
//      __launch_bounds__(256,3): 3 blocks/CU = 12 waves (was ~4 effective,
//      OccupancyPercent 12.8), and the whole 512-block grid co-resident.
// ---------------------------------------------------------------------------
__global__ __launch_bounds__(256, 3) void attn_kernel(
    const bf16* __restrict__ qws, const bf16* __restrict__ kws,
    const bf16* __restrict__ vtws, float* __restrict__ out) {
  __shared__ __align__(16) bf16 Kld[2][8192];
  __shared__ __align__(16) bf16 Plds[4][16][72];

  const int tid = threadIdx.x, lane = tid & 63, wave = tid >> 6;
  const int q4 = lane >> 4, c = lane & 15;
  const int h = blockIdx.y, b = blockIdx.z;
  const int qt = b ? blockIdx.x : (15 - blockIdx.x);  // CU-pair balance
  const size_t bh = (size_t)(b * Hq + h);
  const bf16* qbase = qws + bh * Sq * Dq;
  const bf16* kbase = kws + bh * Sq * Dq;
  const bf16* vbase = vtws + bh * Dq * Sq;
  const int q0 = qt * 128 + wave * 32;
  const float kSc = 0.08838834764831845f * 1.4426950408889634f;

  bf16x8 qf[2][4];
#pragma unroll
  for (int g = 0; g < 2; ++g)
#pragma unroll
    for (int ks = 0; ks < 4; ++ks)
      qf[g][ks] = *(const bf16x8*)
          &qbase[(size_t)(q0 + g * 16 + c) * Dq + ks * 32 + q4 * 8];

  f32x4 Ot[2][8];
  float m_i[2], l_i[2];
#pragma unroll
  for (int g = 0; g < 2; ++g) {
#pragma unroll
    for (int dj = 0; dj < 8; ++dj) Ot[g][dj] = {0.f, 0.f, 0.f, 0.f};
    m_i[g] = -1e30f; l_i[g] = 0.f;
  }

  const int nchunks = 2 * qt + 2;

#pragma unroll
  for (int it = 0; it < 4; ++it) {
    const int slot = it * 256 + tid;
    GLOAD_LDS16(kbase + (size_t)(slot & 63) * Dq + (slot >> 6) * 8,
                &Kld[0][slot * 8]);
  }
  __syncthreads();

  for (int kb = 0; kb < nchunks; ++kb) {
    const int buf = kb & 1;
    if (kb + 1 < nchunks) {
      const int nb = buf ^ 1;
      const int koff = (kb + 1) * 64;
#pragma unroll
      for (int it = 0; it < 4; ++it) {
        const int slot = it * 256 + tid;
        GLOAD_LDS16(kbase + (size_t)(koff + (slot & 63)) * Dq + (slot >> 6) * 8,
                    &Kld[nb][slot * 8]);
      }
    }
    const bool masked = (kb >= 2 * qt);
#pragma unroll
    for (int g = 0; g < 2; ++g) {
      const int qg = q0 + g * 16 + c;
      f32x4 st[4];
#pragma unroll
      for (int j8 = 0; j8 < 4; ++j8) st[j8] = {0.f, 0.f, 0.f, 0.f};
      __builtin_amdgcn_s_setprio(1);
#pragma unroll
      for (int ks = 0; ks < 4; ++ks) {
        const bf16x8 qv = qf[g][ks];
#pragma unroll
        for (int j8 = 0; j8 < 4; ++j8) {
          const bf16x8 kv = *(const bf16x8*)
              &Kld[buf][((ks * 4 + q4) * 64 + j8 * 16 + c) * 8];
          st[j8] = MFMA16(kv, qv, st[j8]);
        }
      }
      __builtin_amdgcn_s_setprio(0);
      if (masked) {
        const int kb64 = kb * 64 + q4 * 4;
#pragma unroll
        for (int j8 = 0; j8 < 4; ++j8)
#pragma unroll
          for (int rr = 0; rr < 4; ++rr)
            if (kb64 + j8 * 16 + rr > qg) st[j8][rr] = -1e30f;
      }
      float mloc = -1e30f;
#pragma unroll
      for (int j8 = 0; j8 < 4; ++j8)
#pragma unroll
        for (int rr = 0; rr < 4; ++rr) mloc = fmaxf(mloc, st[j8][rr]);
      mloc = fmaxf(mloc, __shfl_xor(mloc, 16, 64));
      mloc = fmaxf(mloc, __shfl_xor(mloc, 32, 64));
      const float mn = fmaxf(m_i[g], mloc);
      const float alpha = exp2f((m_i[g] - mn) * kSc);
      m_i[g] = mn;
      float ssum = 0.f;
#pragma unroll
      for (int j8 = 0; j8 < 4; ++j8)
#pragma unroll
        for (int rr = 0; rr < 4; ++rr) {
          const float p = exp2f((st[j8][rr] - mn) * kSc);
          st[j8][rr] = p;
          ssum += p;
        }
      ssum += __shfl_xor(ssum, 16, 64);
      ssum += __shfl_xor(ssum, 32, 64);
      l_i[g] = l_i[g] * alpha + ssum;
#pragma unroll
      for (int dj = 0; dj < 8; ++dj) Ot[g][dj] *= alpha;
#pragma unroll
      for (int j8 = 0; j8 < 4; ++j8) {
        bf16x4 pk;
        pk[0] = f2bf(st[j8][0]); pk[1] = f2bf(st[j8][1]);
        pk[2] = f2bf(st[j8][2]); pk[3] = f2bf(st[j8][3]);
        *(bf16x4*)&Plds[wave][c][j8 * 16 + q4 * 4] = pk;
      }
      __builtin_amdgcn_s_setprio(1);
#pragma unroll
      for (int ks = 0; ks < 2; ++ks) {
        const bf16x8 pv = *(const bf16x8*)&Plds[wave][c][ks * 32 + q4 * 8];
        const bf16* vcol = vbase + (size_t)kb * 64 + (ks * 4 + q4) * 8;
#pragma unroll
        for (int dj = 0; dj < 8; ++dj) {
          const bf16x8 vv =
              *(const bf16x8*)&vcol[(size_t)(dj * 16 + c) * Sq];
          Ot[g][dj] = MFMA16(vv, pv, Ot[g][dj]);
        }
      }
      __builtin_amdgcn_s_setprio(0);
    }
    __syncthreads();
  }

#pragma unroll
  for (int g = 0; g < 2; ++g) {
    const float inv = 1.0f / l_i[g];
    float* orow = out + ((size_t)b * Sq + q0 + g * 16 + c) * Eq + h * Dq;
#pragma unroll
    for (int dj = 0; dj < 8; ++dj) {
      float4 o;
      o.x = Ot[g][dj][0] * inv; o.y = Ot[g][dj][1] * inv;
      o.z = Ot[g][dj][2] * inv; o.w = Ot[g][dj][3] * inv;
      *(float4*)&orow[dj * 16 + q4 * 4] = o;
    }
  }
}

// ---------------------------------------------------------------------------
extern "C" void kernel_launch(void* const* d_in, const int* in_sizes, int n_in,
                              void* d_out, int out_size, void* d_ws,
                              size_t ws_size, hipStream_t stream) {
  const float* x = (const float*)d_in[0];
  // d_in[1] = mask (causal tril) — implemented analytically, not read.
  const float* w = (const float*)d_in[2];
  float* out = (float*)d_out;

  const size_t nX = (size_t)Bq * Sq * Eq;         // 8,388,608
  const size_t nW = (size_t)Eq * N3E;             // 12,582,912
  const size_t perT = (size_t)Bq * Hq * Sq * Dq;  // 8,388,608

  bf16* xb = (bf16*)d_ws;
  bf16* wt = xb + nX;
  bf16* qws = wt + nW;
  bf16* kws = qws + perT;
  bf16* vtws = kws + perT;
  float2* tbl = (float2*)(vtws + perT);  // 2048*64 float2 = 1 MB

  // Fused prep: 4096 (x) + 3072 (wt) + 512 (rope) = 7680 blocks.
  prep<<<7680, 256, 0, stream>>>(x, xb, w, wt, tbl);

  gemm_qkv<<<768, 512, 0, stream>>>(xb, wt, tbl, qws, kws, vtws);

  dim3 g3(Sq / 128, Hq, Bq);  // 16 x 16 x 2, qt CU-paired
  attn_kernel<<<g3, 256, 0, stream>>>(qws, kws, vtws, out);
}

// Round 8
// 396.707 us; speedup vs baseline: 1.3112x; 1.3112x over previous
//
#include <hip/hip_runtime.h>

typedef __bf16 bf16;
typedef __bf16 bf16x8 __attribute__((ext_vector_type(8)));
typedef __bf16 bf16x4 __attribute__((ext_vector_type(4)));
typedef float f32x4 __attribute__((ext_vector_type(4)));

#define MFMA16(a, b, c) __builtin_amdgcn_mfma_f32_16x16x32_bf16(a, b, c, 0, 0, 0)

// Problem constants
#define Bq 2
#define Sq 2048
#define Eq 2048
#define Hq 16
#define Dq 128
#define N3E 6144

#define GLOAD_LDS16(gp, lp) \
  __builtin_amdgcn_global_load_lds( \
      (const __attribute__((address_space(1))) void*)(gp), \
      (__attribute__((address_space(3))) void*)(lp), 16, 0, 0)

__device__ __forceinline__ bf16 f2bf(float f) {
  unsigned u = __builtin_bit_cast(unsigned, f);
  u += 0x7FFFu + ((u >> 16) & 1u);
  unsigned short h = (unsigned short)(u >> 16);
  return __builtin_bit_cast(bf16, h);
}
__device__ __forceinline__ float bf2f(bf16 b) {
  unsigned short h = __builtin_bit_cast(unsigned short, b);
  return __builtin_bit_cast(float, (unsigned)h << 16);
}

// ---------------------------------------------------------------------------
// Kernel 0 (fused prep): blocks [0,4096) convert x; [4096,7168) transpose W;
// [7168,7680) RoPE table.
// ---------------------------------------------------------------------------
__global__ __launch_bounds__(256) void prep(const float* __restrict__ x,
                                            bf16* __restrict__ xb,
                                            const float* __restrict__ w,
                                            bf16* __restrict__ wt,
                                            float2* __restrict__ tbl) {
  __shared__ __align__(16) bf16 T[64][72];
  const int tid = threadIdx.x;
  const int bidx = blockIdx.x;

  if (bidx < 4096) {
    const size_t i = ((size_t)bidx * 256 + tid) * 8;
    float4 a = *(const float4*)(x + i);
    float4 b = *(const float4*)(x + i + 4);
    bf16x8 o;
    o[0] = f2bf(a.x); o[1] = f2bf(a.y); o[2] = f2bf(a.z); o[3] = f2bf(a.w);
    o[4] = f2bf(b.x); o[5] = f2bf(b.y); o[6] = f2bf(b.z); o[7] = f2bf(b.w);
    *(bf16x8*)(xb + i) = o;
  } else if (bidx < 4096 + 3072) {
    const int b2 = bidx - 4096;
    const int kb = b2 & 31;  // 2048/64
    const int nb = b2 >> 5;  // 6144/64
    const int k0 = kb * 64, n0 = nb * 64;
    {
      const int kr = tid >> 4, nc = (tid & 15) * 4;
#pragma unroll
      for (int p = 0; p < 4; ++p) {
        const int k = kr + p * 16;
        float4 v = *(const float4*)(w + (size_t)(k0 + k) * N3E + n0 + nc);
        T[nc + 0][k] = f2bf(v.x);
        T[nc + 1][k] = f2bf(v.y);
        T[nc + 2][k] = f2bf(v.z);
        T[nc + 3][k] = f2bf(v.w);
      }
    }
    __syncthreads();
#pragma unroll
    for (int q = 0; q < 2; ++q) {
      const int id = q * 256 + tid;
      const int n = id >> 3, ch = id & 7;
      bf16x8 v = *(const bf16x8*)&T[n][ch * 8];
      *(bf16x8*)(wt + (size_t)(n0 + n) * Eq + k0 + ch * 8) = v;
    }
  } else {
    const int i = (bidx - 7168) * 256 + tid;  // 0 .. Sq*64-1
    const int s = i >> 6, d = i & 63;
    const float freq = __expf(-(float)d * 0.14391157f);  // ln(10000)/64
    const float ang = (float)s * freq;
    float sv, cv;
    __sincosf(ang, &sv, &cv);
    tbl[i] = make_float2(cv, sv);
  }
}

// ---------------------------------------------------------------------------
// Kernel 1: qkv = xb @ wt^T. ROUND-1 STRUCTURE VERBATIM (proven 123-124 us
// across 4 measurements): 128x256 tile, BK=64, ring-3 LDS (144 KiB), 512
// threads = 8 waves (2Mx4N, 64x64/wave), counted s_waitcnt vmcnt(6).
// ---------------------------------------------------------------------------
__global__ __launch_bounds__(512, 2) void gemm_qkv(
    const bf16* __restrict__ xb, const bf16* __restrict__ wt,
    const float2* __restrict__ tbl, bf16* __restrict__ qws,
    bf16* __restrict__ kws, bf16* __restrict__ vtws) {
  __shared__ __align__(16) bf16 LDS[3 * 24576];

  const int tid = threadIdx.x;
  const int lane = tid & 63, wv = tid >> 6;
  const int q4 = lane >> 4, c = lane & 15;
  const int wm = (wv >> 2) * 64;
  const int wn = (wv & 3) * 64;
  const int cx = c & 7;

  const int bid = blockIdx.x;
  const int wg = (bid & 7) * 96 + (bid >> 3);
  const int m0 = (wg / 24) * 128;
  const int n0 = (wg % 24) * 256;

  f32x4 acc[4][4];
#pragma unroll
  for (int i = 0; i < 4; ++i)
#pragma unroll
    for (int j = 0; j < 4; ++j) acc[i][j] = {0.f, 0.f, 0.f, 0.f};

  const int NT = Eq / 64;

  auto stage = [&](int t, int st) {
    bf16* ab = LDS + st * 24576;
    bf16* bb = ab + 8192;
    const int k0 = t * 64;
#pragma unroll
    for (int it = 0; it < 2; ++it) {
      const int slot = it * 512 + tid;
      const int row = slot >> 3, kch = slot & 7;
      const int kcs = kch ^ (row & 7);
      GLOAD_LDS16(xb + (size_t)(m0 + row) * Eq + k0 + kcs * 8, ab + slot * 8);
    }
#pragma unroll
    for (int it = 0; it < 4; ++it) {
      const int slot = it * 512 + tid;
      const int row = slot >> 3, kch = slot & 7;
      const int kcs = kch ^ (row & 7);
      GLOAD_LDS16(wt + (size_t)(n0 + row) * Eq + k0 + kcs * 8, bb + slot * 8);
    }
  };

  stage(0, 0);
  stage(1, 1);
  asm volatile("s_waitcnt vmcnt(6)" ::: "memory");
  __builtin_amdgcn_s_barrier();

  int stC = 0;
#pragma unroll 1
  for (int t = 0; t < NT; ++t) {
    if (t + 2 < NT) {
      int ss = stC + 2;
      if (ss >= 3) ss -= 3;
      stage(t + 2, ss);
    }
    const bf16* A = LDS + stC * 24576;
    const bf16* Bb = A + 8192;
#pragma unroll
    for (int kk = 0; kk < 64; kk += 32) {
      const int bch = kk >> 3;
      bf16x8 af[4], bfr[4];
#pragma unroll
      for (int i = 0; i < 4; ++i)
        af[i] = *(const bf16x8*)
            &A[(wm + i * 16 + c) * 64 + ((bch + q4) ^ cx) * 8];
#pragma unroll
      for (int j = 0; j < 4; ++j)
        bfr[j] = *(const bf16x8*)
            &Bb[(wn + j * 16 + c) * 64 + ((bch + q4) ^ cx) * 8];
      __builtin_amdgcn_s_setprio(1);
#pragma unroll
      for (int i = 0; i < 4; ++i)
#pragma unroll
        for (int j = 0; j < 4; ++j)
          acc[i][j] = MFMA16(af[i], bfr[j], acc[i][j]);
      __builtin_amdgcn_s_setprio(0);
    }
    if (t + 1 < NT) {
      if (t + 2 < NT) asm volatile("s_waitcnt vmcnt(6)" ::: "memory");
      else            asm volatile("s_waitcnt vmcnt(0)" ::: "memory");
      __builtin_amdgcn_s_barrier();
    }
    stC = stC == 2 ? 0 : stC + 1;
  }
  __syncthreads();

  const int t3 = n0 >> 11;
  const int b = m0 >> 11;
  const int s0 = m0 & 2047;
  const int h0 = (n0 & 2047) >> 7;

  bf16* E = LDS;

  if (t3 == 2) {
#pragma unroll 1
    for (int hh = 0; hh < 2; ++hh) {
      if (((wv & 3) >> 1) == hh) {
#pragma unroll
        for (int i = 0; i < 4; ++i)
#pragma unroll
          for (int j = 0; j < 4; ++j) {
            bf16x4 pv;
            pv[0] = f2bf(acc[i][j][0]); pv[1] = f2bf(acc[i][j][1]);
            pv[2] = f2bf(acc[i][j][2]); pv[3] = f2bf(acc[i][j][3]);
            *(bf16x4*)&E[((wn & 127) + j * 16 + c) * 136 + wm + i * 16 +
                         q4 * 4] = pv;
          }
      }
      __syncthreads();
      bf16* vbase = vtws + ((size_t)(b * Hq + h0 + hh) * Dq) * Sq + s0;
#pragma unroll
      for (int p = 0; p < 4; ++p) {
        const int id = p * 512 + tid;
        const int d = id >> 4, ch = id & 15;
        bf16x8 v = *(const bf16x8*)&E[d * 136 + ch * 8];
        *(bf16x8*)&vbase[(size_t)d * Sq + ch * 8] = v;
      }
      __syncthreads();
    }
  } else {
#pragma unroll 1
    for (int hh = 0; hh < 2; ++hh) {
      if (((wv & 3) >> 1) == hh) {
#pragma unroll
        for (int i = 0; i < 4; ++i)
#pragma unroll
          for (int j = 0; j < 4; ++j)
#pragma unroll
            for (int rr = 0; rr < 4; ++rr)
              E[(wm + i * 16 + q4 * 4 + rr) * 136 + (wn & 127) + j * 16 + c] =
                  f2bf(acc[i][j][rr]);
      }
      __syncthreads();
      bf16* hd = ((t3 == 0) ? qws : kws) +
                 ((size_t)(b * Hq + h0 + hh) * Sq + s0) * Dq;
#pragma unroll
      for (int p = 0; p < 2; ++p) {
        const int row = p * 64 + (tid >> 3);
        const int dlow = (tid & 7) * 8;
        const int s = s0 + row;
        bf16x8 lo = *(const bf16x8*)&E[row * 136 + dlow];
        bf16x8 hi = *(const bf16x8*)&E[row * 136 + 64 + dlow];
        const float2* tb = tbl + (size_t)s * 64 + dlow;
        bf16x8 olo, ohi;
#pragma unroll
        for (int e = 0; e < 8; ++e) {
          const float cv = tb[e].x, sv = tb[e].y;
          const float x1 = bf2f(lo[e]), x2 = bf2f(hi[e]);
          olo[e] = f2bf(x1 * cv - x2 * sv);
          ohi[e] = f2bf(x2 * cv + x1 * sv);
        }
        *(bf16x8*)&hd[(size_t)row * Dq + dlow] = olo;
        *(bf16x8*)&hd[(size_t)row * Dq + 64 + dlow] = ohi;
      }
      __syncthreads();
    }
  }
}

#define KSC (0.08838834764831845f * 1.4426950408889634f)

// ---------------------------------------------------------------------------
// Kernel 3: flash attention, R6 inner structure verbatim (K/V LDS dbuf +
// T13 defer-max + setprio; the only attn config directly measured: 127 us).
// ROUND-8 change: SPLIT-K for heavy tiles. blockIdx.x in [0,24):
//   xid <  16: qt = 15-(xid>>1) in [8,15], s = xid&1 -> chunks
//              [s*(qt+1), (s+1)*(qt+1))  (each half qt+1 chunks, <= 16);
//              writes f32 partials (O, m, l) for later combine.
//   xid >= 16: qt = 23-xid in [0,7], full range [0, 2qt+2), writes out.
// Max per-block sequential chain: 32 -> 16 chunks (the measured tail:
// Occupancy 12.8% = long blocks running solo). Heavy halves ordered first.
// ---------------------------------------------------------------------------
__global__ __launch_bounds__(256, 2) void attn_kernel(
    const bf16* __restrict__ qws, const bf16* __restrict__ kws,
    const bf16* __restrict__ vtws, float* __restrict__ out,
    float* __restrict__ opart, float* __restrict__ ml) {
  __shared__ __align__(16) bf16 Kld[2][8192];
  __shared__ __align__(16) bf16 Vld[2][8192];
  __shared__ __align__(16) bf16 Plds[4][16][72];

  const int tid = threadIdx.x, lane = tid & 63, wave = tid >> 6;
  const int q4 = lane >> 4, c = lane & 15;
  const int h = blockIdx.y, b = blockIdx.z;

  // work mapping: heavy (split) tiles first
  const int xid = blockIdx.x;
  int qt, c0, c1, sp;
  bool split;
  if (xid < 16) {
    split = true;
    qt = 15 - (xid >> 1);
    sp = xid & 1;
    c0 = sp * (qt + 1);
    c1 = c0 + (qt + 1);
  } else {
    split = false;
    qt = 23 - xid;
    sp = 0;
    c0 = 0;
    c1 = 2 * qt + 2;
  }

  const size_t bh = (size_t)(b * Hq + h);
  const bf16* qbase = qws + bh * Sq * Dq;
  const bf16* kbase = kws + bh * Sq * Dq;
  const bf16* vbase = vtws + bh * Dq * Sq;
  const int q0 = qt * 128 + wave * 32;

  bf16x8 qf[2][4];
#pragma unroll
  for (int g = 0; g < 2; ++g)
#pragma unroll
    for (int ks = 0; ks < 4; ++ks)
      qf[g][ks] = *(const bf16x8*)
          &qbase[(size_t)(q0 + g * 16 + c) * Dq + ks * 32 + q4 * 8];

  f32x4 Ot[2][8];
  float m_i[2], l_i[2];
#pragma unroll
  for (int g = 0; g < 2; ++g) {
#pragma unroll
    for (int dj = 0; dj < 8; ++dj) Ot[g][dj] = {0.f, 0.f, 0.f, 0.f};
    m_i[g] = -1e30f; l_i[g] = 0.f;
  }

  {
    const int koff0 = c0 * 64;
#pragma unroll
    for (int it = 0; it < 4; ++it) {
      const int slot = it * 256 + tid;
      GLOAD_LDS16(kbase + (size_t)(koff0 + (slot & 63)) * Dq + (slot >> 6) * 8,
                  &Kld[c0 & 1][slot * 8]);
      GLOAD_LDS16(vbase + (size_t)(slot & 127) * Sq + koff0 + (slot >> 7) * 8,
                  &Vld[c0 & 1][slot * 8]);
    }
  }
  __syncthreads();

  for (int kb = c0; kb < c1; ++kb) {
    const int buf = kb & 1;
    if (kb + 1 < c1) {
      const int nb = buf ^ 1;
      const int koff = (kb + 1) * 64;
#pragma unroll
      for (int it = 0; it < 4; ++it) {
        const int slot = it * 256 + tid;
        GLOAD_LDS16(kbase + (size_t)(koff + (slot & 63)) * Dq + (slot >> 6) * 8,
                    &Kld[nb][slot * 8]);
        GLOAD_LDS16(vbase + (size_t)(slot & 127) * Sq + koff + (slot >> 7) * 8,
                    &Vld[nb][slot * 8]);
      }
    }
    const bool masked = (kb >= 2 * qt);
#pragma unroll
    for (int g = 0; g < 2; ++g) {
      const int qg = q0 + g * 16 + c;
      f32x4 st[4];
#pragma unroll
      for (int j8 = 0; j8 < 4; ++j8) st[j8] = {0.f, 0.f, 0.f, 0.f};
      __builtin_amdgcn_s_setprio(1);
#pragma unroll
      for (int ks = 0; ks < 4; ++ks) {
        const bf16x8 qv = qf[g][ks];
#pragma unroll
        for (int j8 = 0; j8 < 4; ++j8) {
          const bf16x8 kv = *(const bf16x8*)
              &Kld[buf][((ks * 4 + q4) * 64 + j8 * 16 + c) * 8];
          st[j8] = MFMA16(kv, qv, st[j8]);
        }
      }
      __builtin_amdgcn_s_setprio(0);
      if (masked) {
        const int kb64 = kb * 64 + q4 * 4;
#pragma unroll
        for (int j8 = 0; j8 < 4; ++j8)
#pragma unroll
          for (int rr = 0; rr < 4; ++rr)
            if (kb64 + j8 * 16 + rr > qg) st[j8][rr] = -1e30f;
      }
      float mloc = -1e30f;
#pragma unroll
      for (int j8 = 0; j8 < 4; ++j8)
#pragma unroll
        for (int rr = 0; rr < 4; ++rr) mloc = fmaxf(mloc, st[j8][rr]);
      mloc = fmaxf(mloc, __shfl_xor(mloc, 16, 64));
      mloc = fmaxf(mloc, __shfl_xor(mloc, 32, 64));
      // T13 defer-max (as in the measured R6 config)
      float mn = m_i[g];
      if (__any(mloc > mn)) {
        mn = fmaxf(mn, mloc);
        const float alpha = exp2f((m_i[g] - mn) * KSC);
        m_i[g] = mn;
        l_i[g] *= alpha;
#pragma unroll
        for (int dj = 0; dj < 8; ++dj) Ot[g][dj] *= alpha;
      }
      float ssum = 0.f;
#pragma unroll
      for (int j8 = 0; j8 < 4; ++j8)
#pragma unroll
        for (int rr = 0; rr < 4; ++rr) {
          const float p = exp2f((st[j8][rr] - mn) * KSC);
          st[j8][rr] = p;
          ssum += p;
        }
      ssum += __shfl_xor(ssum, 16, 64);
      ssum += __shfl_xor(ssum, 32, 64);
      l_i[g] += ssum;
#pragma unroll
      for (int j8 = 0; j8 < 4; ++j8) {
        bf16x4 pk;
        pk[0] = f2bf(st[j8][0]); pk[1] = f2bf(st[j8][1]);
        pk[2] = f2bf(st[j8][2]); pk[3] = f2bf(st[j8][3]);
        *(bf16x4*)&Plds[wave][c][j8 * 16 + q4 * 4] = pk;
      }
      __builtin_amdgcn_s_setprio(1);
#pragma unroll
      for (int ks = 0; ks < 2; ++ks) {
        const bf16x8 pv = *(const bf16x8*)&Plds[wave][c][ks * 32 + q4 * 8];
#pragma unroll
        for (int dj = 0; dj < 8; ++dj) {
          const bf16x8 vv = *(const bf16x8*)
              &Vld[buf][((ks * 4 + q4) * 128 + dj * 16 + c) * 8];
          Ot[g][dj] = MFMA16(vv, pv, Ot[g][dj]);
        }
      }
      __builtin_amdgcn_s_setprio(0);
    }
    __syncthreads();
  }

  if (!split) {
#pragma unroll
    for (int g = 0; g < 2; ++g) {
      const float inv = 1.0f / l_i[g];
      float* orow = out + ((size_t)b * Sq + q0 + g * 16 + c) * Eq + h * Dq;
#pragma unroll
      for (int dj = 0; dj < 8; ++dj) {
        float4 o;
        o.x = Ot[g][dj][0] * inv; o.y = Ot[g][dj][1] * inv;
        o.z = Ot[g][dj][2] * inv; o.w = Ot[g][dj][3] * inv;
        *(float4*)&orow[dj * 16 + q4 * 4] = o;
      }
    }
  } else {
    // tix: ((b*Hq+h)*8 + (qt-8))*2 + s
    const int tix = (((b * Hq + h) * 8) + (qt - 8)) * 2 + sp;
#pragma unroll
    for (int g = 0; g < 2; ++g) {
      const int wrow = wave * 32 + g * 16 + c;
      float* prow = opart + ((size_t)tix * 128 + wrow) * 128;
#pragma unroll
      for (int dj = 0; dj < 8; ++dj) {
        float4 o;
        o.x = Ot[g][dj][0]; o.y = Ot[g][dj][1];
        o.z = Ot[g][dj][2]; o.w = Ot[g][dj][3];
        *(float4*)&prow[dj * 16 + q4 * 4] = o;
      }
      if (q4 == 0) {
        ml[((size_t)tix * 128 + wrow) * 2 + 0] = m_i[g];
        ml[((size_t)tix * 128 + wrow) * 2 + 1] = l_i[g];
      }
    }
  }
}

// ---------------------------------------------------------------------------
// Kernel 4: combine the two split-K halves for qt>=8 tiles.
// tile = blockIdx.x in [0,256): tile = (b*16+h)*8 + (qt-8).
// thread t: row = t>>1 (128 rows), d-half = (t&1)*64.
// ---------------------------------------------------------------------------
__global__ __launch_bounds__(256) void attn_combine(
    const float* __restrict__ opart, const float* __restrict__ ml,
    float* __restrict__ out) {
  const int tile = blockIdx.x;
  const int qt = (tile & 7) + 8;
  const int hb = tile >> 3;
  const int h = hb & 15, b = hb >> 4;
  const int tid = threadIdx.x;
  const int r = tid >> 1;
  const int d0 = (tid & 1) * 64;
  const int t0 = tile * 2, t1 = t0 + 1;

  const float m0 = ml[((size_t)t0 * 128 + r) * 2 + 0];
  const float l0 = ml[((size_t)t0 * 128 + r) * 2 + 1];
  const float m1 = ml[((size_t)t1 * 128 + r) * 2 + 0];
  const float l1 = ml[((size_t)t1 * 128 + r) * 2 + 1];
  const float m = fmaxf(m0, m1);
  const float w0 = exp2f((m0 - m) * KSC);
  const float w1 = exp2f((m1 - m) * KSC);
  const float inv = 1.0f / (l0 * w0 + l1 * w1);
  const float s0 = w0 * inv, s1 = w1 * inv;

  const float* p0 = opart + ((size_t)t0 * 128 + r) * 128 + d0;
  const float* p1 = opart + ((size_t)t1 * 128 + r) * 128 + d0;
  float* orow = out + ((size_t)(b * Sq + qt * 128 + r)) * Eq + h * Dq + d0;
#pragma unroll
  for (int i = 0; i < 16; ++i) {
    float4 a = *(const float4*)&p0[i * 4];
    float4 bb = *(const float4*)&p1[i * 4];
    float4 o;
    o.x = a.x * s0 + bb.x * s1;
    o.y = a.y * s0 + bb.y * s1;
    o.z = a.z * s0 + bb.z * s1;
    o.w = a.w * s0 + bb.w * s1;
    *(float4*)&orow[i * 4] = o;
  }
}

// ---------------------------------------------------------------------------
extern "C" void kernel_launch(void* const* d_in, const int* in_sizes, int n_in,
                              void* d_out, int out_size, void* d_ws,
                              size_t ws_size, hipStream_t stream) {
  const float* x = (const float*)d_in[0];
  // d_in[1] = mask (causal tril) — implemented analytically, not read.
  const float* w = (const float*)d_in[2];
  float* out = (float*)d_out;

  const size_t nX = (size_t)Bq * Sq * Eq;         // 8,388,608
  const size_t nW = (size_t)Eq * N3E;             // 12,582,912
  const size_t perT = (size_t)Bq * Hq * Sq * Dq;  // 8,388,608

  bf16* xb = (bf16*)d_ws;
  bf16* wt = xb + nX;
  bf16* qws = wt + nW;
  bf16* kws = qws + perT;
  bf16* vtws = kws + perT;
  float2* tbl = (float2*)(vtws + perT);  // 2048*64 float2 = 1 MB

  // Split-K partials ALIAS the xb/wt region (41.9 MB; dead after gemm):
  //   opart: 512 tile-halves x 128 rows x 128 d f32 = 33.55 MB
  //   ml:    512 x 128 x 2 f32 = 0.5 MB
  float* opart = (float*)d_ws;
  float* ml = opart + (size_t)512 * 128 * 128;

  prep<<<7680, 256, 0, stream>>>(x, xb, w, wt, tbl);

  gemm_qkv<<<768, 512, 0, stream>>>(xb, wt, tbl, qws, kws, vtws);

  dim3 g3(24, 16, 2);  // heavy (split) tiles first in x
  attn_kernel<<<g3, 256, 0, stream>>>(qws, kws, vtws, out, opart, ml);

  attn_combine<<<256, 256, 0, stream>>>(opart, ml, out);
}

// Round 9
// 371.258 us; speedup vs baseline: 1.4011x; 1.0685x over previous
//
#include <hip/hip_runtime.h>

typedef __bf16 bf16;
typedef __bf16 bf16x8 __attribute__((ext_vector_type(8)));
typedef __bf16 bf16x4 __attribute__((ext_vector_type(4)));
typedef float f32x4 __attribute__((ext_vector_type(4)));

#define MFMA16(a, b, c) __builtin_amdgcn_mfma_f32_16x16x32_bf16(a, b, c, 0, 0, 0)

// Problem constants
#define Bq 2
#define Sq 2048
#define Eq 2048
#define Hq 16
#define Dq 128
#define N3E 6144

#define GLOAD_LDS16(gp, lp) \
  __builtin_amdgcn_global_load_lds( \
      (const __attribute__((address_space(1))) void*)(gp), \
      (__attribute__((address_space(3))) void*)(lp), 16, 0, 0)

__device__ __forceinline__ bf16 f2bf(float f) {
  unsigned u = __builtin_bit_cast(unsigned, f);
  u += 0x7FFFu + ((u >> 16) & 1u);
  unsigned short h = (unsigned short)(u >> 16);
  return __builtin_bit_cast(bf16, h);
}
__device__ __forceinline__ float bf2f(bf16 b) {
  unsigned short h = __builtin_bit_cast(unsigned short, b);
  return __builtin_bit_cast(float, (unsigned)h << 16);
}

// ---------------------------------------------------------------------------
// Kernel 0 (fused prep): blocks [0,4096) convert x; [4096,7168) transpose W;
// [7168,7680) RoPE table.
// ---------------------------------------------------------------------------
__global__ __launch_bounds__(256) void prep(const float* __restrict__ x,
                                            bf16* __restrict__ xb,
                                            const float* __restrict__ w,
                                            bf16* __restrict__ wt,
                                            float2* __restrict__ tbl) {
  __shared__ __align__(16) bf16 T[64][72];
  const int tid = threadIdx.x;
  const int bidx = blockIdx.x;

  if (bidx < 4096) {
    const size_t i = ((size_t)bidx * 256 + tid) * 8;
    float4 a = *(const float4*)(x + i);
    float4 b = *(const float4*)(x + i + 4);
    bf16x8 o;
    o[0] = f2bf(a.x); o[1] = f2bf(a.y); o[2] = f2bf(a.z); o[3] = f2bf(a.w);
    o[4] = f2bf(b.x); o[5] = f2bf(b.y); o[6] = f2bf(b.z); o[7] = f2bf(b.w);
    *(bf16x8*)(xb + i) = o;
  } else if (bidx < 4096 + 3072) {
    const int b2 = bidx - 4096;
    const int kb = b2 & 31;  // 2048/64
    const int nb = b2 >> 5;  // 6144/64
    const int k0 = kb * 64, n0 = nb * 64;
    {
      const int kr = tid >> 4, nc = (tid & 15) * 4;
#pragma unroll
      for (int p = 0; p < 4; ++p) {
        const int k = kr + p * 16;
        float4 v = *(const float4*)(w + (size_t)(k0 + k) * N3E + n0 + nc);
        T[nc + 0][k] = f2bf(v.x);
        T[nc + 1][k] = f2bf(v.y);
        T[nc + 2][k] = f2bf(v.z);
        T[nc + 3][k] = f2bf(v.w);
      }
    }
    __syncthreads();
#pragma unroll
    for (int q = 0; q < 2; ++q) {
      const int id = q * 256 + tid;
      const int n = id >> 3, ch = id & 7;
      bf16x8 v = *(const bf16x8*)&T[n][ch * 8];
      *(bf16x8*)(wt + (size_t)(n0 + n) * Eq + k0 + ch * 8) = v;
    }
  } else {
    const int i = (bidx - 7168) * 256 + tid;  // 0 .. Sq*64-1
    const int s = i >> 6, d = i & 63;
    const float freq = __expf(-(float)d * 0.14391157f);  // ln(10000)/64
    const float ang = (float)s * freq;
    float sv, cv;
    __sincosf(ang, &sv, &cv);
    tbl[i] = make_float2(cv, sv);
  }
}

// ---------------------------------------------------------------------------
// Kernel 1: qkv = xb @ wt^T. ROUND-1 STRUCTURE VERBATIM (proven 123-124 us
// across 5 measurements): 128x256 tile, BK=64, ring-3 LDS (144 KiB), 512
// threads = 8 waves (2Mx4N, 64x64/wave), counted s_waitcnt vmcnt(6).
// ---------------------------------------------------------------------------
__global__ __launch_bounds__(512, 2) void gemm_qkv(
    const bf16* __restrict__ xb, const bf16* __restrict__ wt,
    const float2* __restrict__ tbl, bf16* __restrict__ qws,
    bf16* __restrict__ kws, bf16* __restrict__ vtws) {
  __shared__ __align__(16) bf16 LDS[3 * 24576];

  const int tid = threadIdx.x;
  const int lane = tid & 63, wv = tid >> 6;
  const int q4 = lane >> 4, c = lane & 15;
  const int wm = (wv >> 2) * 64;
  const int wn = (wv & 3) * 64;
  const int cx = c & 7;

  const int bid = blockIdx.x;
  const int wg = (bid & 7) * 96 + (bid >> 3);
  const int m0 = (wg / 24) * 128;
  const int n0 = (wg % 24) * 256;

  f32x4 acc[4][4];
#pragma unroll
  for (int i = 0; i < 4; ++i)
#pragma unroll
    for (int j = 0; j < 4; ++j) acc[i][j] = {0.f, 0.f, 0.f, 0.f};

  const int NT = Eq / 64;

  auto stage = [&](int t, int st) {
    bf16* ab = LDS + st * 24576;
    bf16* bb = ab + 8192;
    const int k0 = t * 64;
#pragma unroll
    for (int it = 0; it < 2; ++it) {
      const int slot = it * 512 + tid;
      const int row = slot >> 3, kch = slot & 7;
      const int kcs = kch ^ (row & 7);
      GLOAD_LDS16(xb + (size_t)(m0 + row) * Eq + k0 + kcs * 8, ab + slot * 8);
    }
#pragma unroll
    for (int it = 0; it < 4; ++it) {
      const int slot = it * 512 + tid;
      const int row = slot >> 3, kch = slot & 7;
      const int kcs = kch ^ (row & 7);
      GLOAD_LDS16(wt + (size_t)(n0 + row) * Eq + k0 + kcs * 8, bb + slot * 8);
    }
  };

  stage(0, 0);
  stage(1, 1);
  asm volatile("s_waitcnt vmcnt(6)" ::: "memory");
  __builtin_amdgcn_s_barrier();

  int stC = 0;
#pragma unroll 1
  for (int t = 0; t < NT; ++t) {
    if (t + 2 < NT) {
      int ss = stC + 2;
      if (ss >= 3) ss -= 3;
      stage(t + 2, ss);
    }
    const bf16* A = LDS + stC * 24576;
    const bf16* Bb = A + 8192;
#pragma unroll
    for (int kk = 0; kk < 64; kk += 32) {
      const int bch = kk >> 3;
      bf16x8 af[4], bfr[4];
#pragma unroll
      for (int i = 0; i < 4; ++i)
        af[i] = *(const bf16x8*)
            &A[(wm + i * 16 + c) * 64 + ((bch + q4) ^ cx) * 8];
#pragma unroll
      for (int j = 0; j < 4; ++j)
        bfr[j] = *(const bf16x8*)
            &Bb[(wn + j * 16 + c) * 64 + ((bch + q4) ^ cx) * 8];
      __builtin_amdgcn_s_setprio(1);
#pragma unroll
      for (int i = 0; i < 4; ++i)
#pragma unroll
        for (int j = 0; j < 4; ++j)
          acc[i][j] = MFMA16(af[i], bfr[j], acc[i][j]);
      __builtin_amdgcn_s_setprio(0);
    }
    if (t + 1 < NT) {
      if (t + 2 < NT) asm volatile("s_waitcnt vmcnt(6)" ::: "memory");
      else            asm volatile("s_waitcnt vmcnt(0)" ::: "memory");
      __builtin_amdgcn_s_barrier();
    }
    stC = stC == 2 ? 0 : stC + 1;
  }
  __syncthreads();

  const int t3 = n0 >> 11;
  const int b = m0 >> 11;
  const int s0 = m0 & 2047;
  const int h0 = (n0 & 2047) >> 7;

  bf16* E = LDS;

  if (t3 == 2) {
#pragma unroll 1
    for (int hh = 0; hh < 2; ++hh) {
      if (((wv & 3) >> 1) == hh) {
#pragma unroll
        for (int i = 0; i < 4; ++i)
#pragma unroll
          for (int j = 0; j < 4; ++j) {
            bf16x4 pv;
            pv[0] = f2bf(acc[i][j][0]); pv[1] = f2bf(acc[i][j][1]);
            pv[2] = f2bf(acc[i][j][2]); pv[3] = f2bf(acc[i][j][3]);
            *(bf16x4*)&E[((wn & 127) + j * 16 + c) * 136 + wm + i * 16 +
                         q4 * 4] = pv;
          }
      }
      __syncthreads();
      bf16* vbase = vtws + ((size_t)(b * Hq + h0 + hh) * Dq) * Sq + s0;
#pragma unroll
      for (int p = 0; p < 4; ++p) {
        const int id = p * 512 + tid;
        const int d = id >> 4, ch = id & 15;
        bf16x8 v = *(const bf16x8*)&E[d * 136 + ch * 8];
        *(bf16x8*)&vbase[(size_t)d * Sq + ch * 8] = v;
      }
      __syncthreads();
    }
  } else {
#pragma unroll 1
    for (int hh = 0; hh < 2; ++hh) {
      if (((wv & 3) >> 1) == hh) {
#pragma unroll
        for (int i = 0; i < 4; ++i)
#pragma unroll
          for (int j = 0; j < 4; ++j)
#pragma unroll
            for (int rr = 0; rr < 4; ++rr)
              E[(wm + i * 16 + q4 * 4 + rr) * 136 + (wn & 127) + j * 16 + c] =
                  f2bf(acc[i][j][rr]);
      }
      __syncthreads();
      bf16* hd = ((t3 == 0) ? qws : kws) +
                 ((size_t)(b * Hq + h0 + hh) * Sq + s0) * Dq;
#pragma unroll
      for (int p = 0; p < 2; ++p) {
        const int row = p * 64 + (tid >> 3);
        const int dlow = (tid & 7) * 8;
        const int s = s0 + row;
        bf16x8 lo = *(const bf16x8*)&E[row * 136 + dlow];
        bf16x8 hi = *(const bf16x8*)&E[row * 136 + 64 + dlow];
        const float2* tb = tbl + (size_t)s * 64 + dlow;
        bf16x8 olo, ohi;
#pragma unroll
        for (int e = 0; e < 8; ++e) {
          const float cv = tb[e].x, sv = tb[e].y;
          const float x1 = bf2f(lo[e]), x2 = bf2f(hi[e]);
          olo[e] = f2bf(x1 * cv - x2 * sv);
          ohi[e] = f2bf(x2 * cv + x1 * sv);
        }
        *(bf16x8*)&hd[(size_t)row * Dq + dlow] = olo;
        *(bf16x8*)&hd[(size_t)row * Dq + 64 + dlow] = ohi;
      }
      __syncthreads();
    }
  }
}

#define KSC (0.08838834764831845f * 1.4426950408889634f)

// ---------------------------------------------------------------------------
// ROUND-9 static schedule: 24 work pieces per (h,b) packed into 16 blocks
// (max 21 chunks/block, vs 32 unsplit). Pieces: heavy tiles qt 8-15 split
// into 2 halves (qt+1 chunks each; partials + combine — machinery verified
// in R8), light tiles qt 0-7 whole (direct out). sp: 0/1 = half, 2 = full.
// Grid (16,16,2) = 512 blocks = resident-slot count (R8's 768-block grid
// caused 2 scheduling rounds -> serial chain back to ~32). ZP permutes the
// schedule for b=1 so CU-paired blocks (id, id+256) sum to 32-35 chunks.
// ---------------------------------------------------------------------------
__device__ const int dSQT0[16] = {15,15, 7,14,14, 6,13,13,12,12,11,11, 8,10,10, 9};
__device__ const int dSSP0[16] = { 0, 1, 2, 0, 1, 2, 0, 1, 0, 1, 0, 1, 0, 0, 1, 0};
__device__ const int dSQT1[16] = {-1,-1,-1,-1,-1,-1,-1,-1, 0, 1, 2, 3, 5, 8, 4, 9};
__device__ const int dSSP1[16] = { 0, 0, 0, 0, 0, 0, 0, 0, 2, 2, 2, 2, 2, 1, 2, 1};
__device__ const int dZP[16]   = { 9, 2, 1,13,15,12,14,11,10, 0, 8, 7, 5, 3, 6, 4};

__global__ __launch_bounds__(256, 2) void attn_kernel(
    const bf16* __restrict__ qws, const bf16* __restrict__ kws,
    const bf16* __restrict__ vtws, float* __restrict__ out,
    float* __restrict__ opart, float* __restrict__ ml) {
  __shared__ __align__(16) bf16 Kld[2][8192];
  __shared__ __align__(16) bf16 Vld[2][8192];
  __shared__ __align__(16) bf16 Plds[4][16][72];

  const int tid = threadIdx.x, lane = tid & 63, wave = tid >> 6;
  const int q4 = lane >> 4, c = lane & 15;
  const int h = blockIdx.y, b = blockIdx.z;
  const int sidx = (b == 0) ? blockIdx.x : dZP[blockIdx.x];

  const size_t bh = (size_t)(b * Hq + h);
  const bf16* qbase = qws + bh * Sq * Dq;
  const bf16* kbase = kws + bh * Sq * Dq;
  const bf16* vbase = vtws + bh * Dq * Sq;

#pragma unroll 1
  for (int seg = 0; seg < 2; ++seg) {
    const int qt = (seg == 0) ? dSQT0[sidx] : dSQT1[sidx];
    if (qt < 0) break;
    const int sp = (seg == 0) ? dSSP0[sidx] : dSSP1[sidx];
    const bool split = (sp != 2);
    const int c0 = split ? sp * (qt + 1) : 0;
    const int c1 = split ? c0 + (qt + 1) : 2 * qt + 2;
    const int q0 = qt * 128 + wave * 32;

    bf16x8 qf[2][4];
#pragma unroll
    for (int g = 0; g < 2; ++g)
#pragma unroll
      for (int ks = 0; ks < 4; ++ks)
        qf[g][ks] = *(const bf16x8*)
            &qbase[(size_t)(q0 + g * 16 + c) * Dq + ks * 32 + q4 * 8];

    f32x4 Ot[2][8];
    float m_i[2], l_i[2];
#pragma unroll
    for (int g = 0; g < 2; ++g) {
#pragma unroll
      for (int dj = 0; dj < 8; ++dj) Ot[g][dj] = {0.f, 0.f, 0.f, 0.f};
      m_i[g] = -1e30f; l_i[g] = 0.f;
    }

    {
      const int koff0 = c0 * 64;
#pragma unroll
      for (int it = 0; it < 4; ++it) {
        const int slot = it * 256 + tid;
        GLOAD_LDS16(
            kbase + (size_t)(koff0 + (slot & 63)) * Dq + (slot >> 6) * 8,
            &Kld[c0 & 1][slot * 8]);
        GLOAD_LDS16(
            vbase + (size_t)(slot & 127) * Sq + koff0 + (slot >> 7) * 8,
            &Vld[c0 & 1][slot * 8]);
      }
    }
    __syncthreads();

    for (int kb = c0; kb < c1; ++kb) {
      const int buf = kb & 1;
      if (kb + 1 < c1) {
        const int nb = buf ^ 1;
        const int koff = (kb + 1) * 64;
#pragma unroll
        for (int it = 0; it < 4; ++it) {
          const int slot = it * 256 + tid;
          GLOAD_LDS16(
              kbase + (size_t)(koff + (slot & 63)) * Dq + (slot >> 6) * 8,
              &Kld[nb][slot * 8]);
          GLOAD_LDS16(
              vbase + (size_t)(slot & 127) * Sq + koff + (slot >> 7) * 8,
              &Vld[nb][slot * 8]);
        }
      }
      const bool masked = (kb >= 2 * qt);
#pragma unroll
      for (int g = 0; g < 2; ++g) {
        const int qg = q0 + g * 16 + c;
        f32x4 st[4];
#pragma unroll
        for (int j8 = 0; j8 < 4; ++j8) st[j8] = {0.f, 0.f, 0.f, 0.f};
        __builtin_amdgcn_s_setprio(1);
#pragma unroll
        for (int ks = 0; ks < 4; ++ks) {
          const bf16x8 qv = qf[g][ks];
#pragma unroll
          for (int j8 = 0; j8 < 4; ++j8) {
            const bf16x8 kv = *(const bf16x8*)
                &Kld[buf][((ks * 4 + q4) * 64 + j8 * 16 + c) * 8];
            st[j8] = MFMA16(kv, qv, st[j8]);
          }
        }
        __builtin_amdgcn_s_setprio(0);
        if (masked) {
          const int kb64 = kb * 64 + q4 * 4;
#pragma unroll
          for (int j8 = 0; j8 < 4; ++j8)
#pragma unroll
            for (int rr = 0; rr < 4; ++rr)
              if (kb64 + j8 * 16 + rr > qg) st[j8][rr] = -1e30f;
        }
        float mloc = -1e30f;
#pragma unroll
        for (int j8 = 0; j8 < 4; ++j8)
#pragma unroll
          for (int rr = 0; rr < 4; ++rr) mloc = fmaxf(mloc, st[j8][rr]);
        mloc = fmaxf(mloc, __shfl_xor(mloc, 16, 64));
        mloc = fmaxf(mloc, __shfl_xor(mloc, 32, 64));
        float mn = m_i[g];
        if (__any(mloc > mn)) {
          mn = fmaxf(mn, mloc);
          const float alpha = exp2f((m_i[g] - mn) * KSC);
          m_i[g] = mn;
          l_i[g] *= alpha;
#pragma unroll
          for (int dj = 0; dj < 8; ++dj) Ot[g][dj] *= alpha;
        }
        float ssum = 0.f;
#pragma unroll
        for (int j8 = 0; j8 < 4; ++j8)
#pragma unroll
          for (int rr = 0; rr < 4; ++rr) {
            const float p = exp2f((st[j8][rr] - mn) * KSC);
            st[j8][rr] = p;
            ssum += p;
          }
        ssum += __shfl_xor(ssum, 16, 64);
        ssum += __shfl_xor(ssum, 32, 64);
        l_i[g] += ssum;
#pragma unroll
        for (int j8 = 0; j8 < 4; ++j8) {
          bf16x4 pk;
          pk[0] = f2bf(st[j8][0]); pk[1] = f2bf(st[j8][1]);
          pk[2] = f2bf(st[j8][2]); pk[3] = f2bf(st[j8][3]);
          *(bf16x4*)&Plds[wave][c][j8 * 16 + q4 * 4] = pk;
        }
        __builtin_amdgcn_s_setprio(1);
#pragma unroll
        for (int ks = 0; ks < 2; ++ks) {
          const bf16x8 pv = *(const bf16x8*)&Plds[wave][c][ks * 32 + q4 * 8];
#pragma unroll
          for (int dj = 0; dj < 8; ++dj) {
            const bf16x8 vv = *(const bf16x8*)
                &Vld[buf][((ks * 4 + q4) * 128 + dj * 16 + c) * 8];
            Ot[g][dj] = MFMA16(vv, pv, Ot[g][dj]);
          }
        }
        __builtin_amdgcn_s_setprio(0);
      }
      __syncthreads();
    }

    if (!split) {
#pragma unroll
      for (int g = 0; g < 2; ++g) {
        const float inv = 1.0f / l_i[g];
        float* orow = out + ((size_t)b * Sq + q0 + g * 16 + c) * Eq + h * Dq;
#pragma unroll
        for (int dj = 0; dj < 8; ++dj) {
          float4 o;
          o.x = Ot[g][dj][0] * inv; o.y = Ot[g][dj][1] * inv;
          o.z = Ot[g][dj][2] * inv; o.w = Ot[g][dj][3] * inv;
          *(float4*)&orow[dj * 16 + q4 * 4] = o;
        }
      }
    } else {
      const int tix = (((b * Hq + h) * 8) + (qt - 8)) * 2 + sp;
#pragma unroll
      for (int g = 0; g < 2; ++g) {
        const int wrow = wave * 32 + g * 16 + c;
        float* prow = opart + ((size_t)tix * 128 + wrow) * 128;
#pragma unroll
        for (int dj = 0; dj < 8; ++dj) {
          float4 o;
          o.x = Ot[g][dj][0]; o.y = Ot[g][dj][1];
          o.z = Ot[g][dj][2]; o.w = Ot[g][dj][3];
          *(float4*)&prow[dj * 16 + q4 * 4] = o;
        }
        if (q4 == 0) {
          ml[((size_t)tix * 128 + wrow) * 2 + 0] = m_i[g];
          ml[((size_t)tix * 128 + wrow) * 2 + 1] = l_i[g];
        }
      }
    }
  }
}

// ---------------------------------------------------------------------------
// Kernel 4: combine the two split-K halves for qt>=8 tiles (R8-verified).
// ---------------------------------------------------------------------------
__global__ __launch_bounds__(256) void attn_combine(
    const float* __restrict__ opart, const float* __restrict__ ml,
    float* __restrict__ out) {
  const int tile = blockIdx.x;
  const int qt = (tile & 7) + 8;
  const int hb = tile >> 3;
  const int h = hb & 15, b = hb >> 4;
  const int tid = threadIdx.x;
  const int r = tid >> 1;
  const int d0 = (tid & 1) * 64;
  const int t0 = tile * 2, t1 = t0 + 1;

  const float m0 = ml[((size_t)t0 * 128 + r) * 2 + 0];
  const float l0 = ml[((size_t)t0 * 128 + r) * 2 + 1];
  const float m1 = ml[((size_t)t1 * 128 + r) * 2 + 0];
  const float l1 = ml[((size_t)t1 * 128 + r) * 2 + 1];
  const float m = fmaxf(m0, m1);
  const float w0 = exp2f((m0 - m) * KSC);
  const float w1 = exp2f((m1 - m) * KSC);
  const float inv = 1.0f / (l0 * w0 + l1 * w1);
  const float s0 = w0 * inv, s1 = w1 * inv;

  const float* p0 = opart + ((size_t)t0 * 128 + r) * 128 + d0;
  const float* p1 = opart + ((size_t)t1 * 128 + r) * 128 + d0;
  float* orow = out + ((size_t)(b * Sq + qt * 128 + r)) * Eq + h * Dq + d0;
#pragma unroll
  for (int i = 0; i < 16; ++i) {
    float4 a = *(const float4*)&p0[i * 4];
    float4 bb = *(const float4*)&p1[i * 4];
    float4 o;
    o.x = a.x * s0 + bb.x * s1;
    o.y = a.y * s0 + bb.y * s1;
    o.z = a.z * s0 + bb.z * s1;
    o.w = a.w * s0 + bb.w * s1;
    *(float4*)&orow[i * 4] = o;
  }
}

// ---------------------------------------------------------------------------
extern "C" void kernel_launch(void* const* d_in, const int* in_sizes, int n_in,
                              void* d_out, int out_size, void* d_ws,
                              size_t ws_size, hipStream_t stream) {
  const float* x = (const float*)d_in[0];
  // d_in[1] = mask (causal tril) — implemented analytically, not read.
  const float* w = (const float*)d_in[2];
  float* out = (float*)d_out;

  const size_t nX = (size_t)Bq * Sq * Eq;         // 8,388,608
  const size_t nW = (size_t)Eq * N3E;             // 12,582,912
  const size_t perT = (size_t)Bq * Hq * Sq * Dq;  // 8,388,608

  bf16* xb = (bf16*)d_ws;
  bf16* wt = xb + nX;
  bf16* qws = wt + nW;
  bf16* kws = qws + perT;
  bf16* vtws = kws + perT;
  float2* tbl = (float2*)(vtws + perT);  // 2048*64 float2 = 1 MB

  // Split-K partials ALIAS the xb/wt region (41.9 MB; dead after gemm):
  //   opart: 512 tile-halves x 128 rows x 128 d f32 = 33.55 MB
  //   ml:    512 x 128 x 2 f32 = 0.5 MB
  float* opart = (float*)d_ws;
  float* ml = opart + (size_t)512 * 128 * 128;

  prep<<<7680, 256, 0, stream>>>(x, xb, w, wt, tbl);

  gemm_qkv<<<768, 512, 0, stream>>>(xb, wt, tbl, qws, kws, vtws);

  dim3 g3(16, 16, 2);  // 512 blocks = resident-slot count; static schedule
  attn_kernel<<<g3, 256, 0, stream>>>(qws, kws, vtws, out, opart, ml);

  attn_combine<<<256, 256, 0, stream>>>(opart, ml, out);
}

// Round 10
// 370.803 us; speedup vs baseline: 1.4028x; 1.0012x over previous
//
#include <hip/hip_runtime.h>

typedef __bf16 bf16;
typedef __bf16 bf16x8 __attribute__((ext_vector_type(8)));
typedef __bf16 bf16x4 __attribute__((ext_vector_type(4)));
typedef float f32x4 __attribute__((ext_vector_type(4)));

#define MFMA16(a, b, c) __builtin_amdgcn_mfma_f32_16x16x32_bf16(a, b, c, 0, 0, 0)

// Problem constants
#define Bq 2
#define Sq 2048
#define Eq 2048
#define Hq 16
#define Dq 128
#define N3E 6144

#define GLOAD_LDS16(gp, lp) \
  __builtin_amdgcn_global_load_lds( \
      (const __attribute__((address_space(1))) void*)(gp), \
      (__attribute__((address_space(3))) void*)(lp), 16, 0, 0)

__device__ __forceinline__ bf16 f2bf(float f) {
  unsigned u = __builtin_bit_cast(unsigned, f);
  u += 0x7FFFu + ((u >> 16) & 1u);
  unsigned short h = (unsigned short)(u >> 16);
  return __builtin_bit_cast(bf16, h);
}
__device__ __forceinline__ float bf2f(bf16 b) {
  unsigned short h = __builtin_bit_cast(unsigned short, b);
  return __builtin_bit_cast(float, (unsigned)h << 16);
}

// ---------------------------------------------------------------------------
// Kernel 0 (fused prep): blocks [0,4096) convert x; [4096,7168) transpose W;
// [7168,7680) RoPE table.
// ---------------------------------------------------------------------------
__global__ __launch_bounds__(256) void prep(const float* __restrict__ x,
                                            bf16* __restrict__ xb,
                                            const float* __restrict__ w,
                                            bf16* __restrict__ wt,
                                            float2* __restrict__ tbl) {
  __shared__ __align__(16) bf16 T[64][72];
  const int tid = threadIdx.x;
  const int bidx = blockIdx.x;

  if (bidx < 4096) {
    const size_t i = ((size_t)bidx * 256 + tid) * 8;
    float4 a = *(const float4*)(x + i);
    float4 b = *(const float4*)(x + i + 4);
    bf16x8 o;
    o[0] = f2bf(a.x); o[1] = f2bf(a.y); o[2] = f2bf(a.z); o[3] = f2bf(a.w);
    o[4] = f2bf(b.x); o[5] = f2bf(b.y); o[6] = f2bf(b.z); o[7] = f2bf(b.w);
    *(bf16x8*)(xb + i) = o;
  } else if (bidx < 4096 + 3072) {
    const int b2 = bidx - 4096;
    const int kb = b2 & 31;  // 2048/64
    const int nb = b2 >> 5;  // 6144/64
    const int k0 = kb * 64, n0 = nb * 64;
    {
      const int kr = tid >> 4, nc = (tid & 15) * 4;
#pragma unroll
      for (int p = 0; p < 4; ++p) {
        const int k = kr + p * 16;
        float4 v = *(const float4*)(w + (size_t)(k0 + k) * N3E + n0 + nc);
        T[nc + 0][k] = f2bf(v.x);
        T[nc + 1][k] = f2bf(v.y);
        T[nc + 2][k] = f2bf(v.z);
        T[nc + 3][k] = f2bf(v.w);
      }
    }
    __syncthreads();
#pragma unroll
    for (int q = 0; q < 2; ++q) {
      const int id = q * 256 + tid;
      const int n = id >> 3, ch = id & 7;
      bf16x8 v = *(const bf16x8*)&T[n][ch * 8];
      *(bf16x8*)(wt + (size_t)(n0 + n) * Eq + k0 + ch * 8) = v;
    }
  } else {
    const int i = (bidx - 7168) * 256 + tid;  // 0 .. Sq*64-1
    const int s = i >> 6, d = i & 63;
    const float freq = __expf(-(float)d * 0.14391157f);  // ln(10000)/64
    const float ang = (float)s * freq;
    float sv, cv;
    __sincosf(ang, &sv, &cv);
    tbl[i] = make_float2(cv, sv);
  }
}

// ---------------------------------------------------------------------------
// Kernel 1: qkv = xb @ wt^T. ROUND-1 STRUCTURE VERBATIM (proven 123-124 us
// across 5 measurements): 128x256 tile, BK=64, ring-3 LDS (144 KiB), 512
// threads = 8 waves (2Mx4N, 64x64/wave), counted s_waitcnt vmcnt(6).
// ---------------------------------------------------------------------------
__global__ __launch_bounds__(512, 2) void gemm_qkv(
    const bf16* __restrict__ xb, const bf16* __restrict__ wt,
    const float2* __restrict__ tbl, bf16* __restrict__ qws,
    bf16* __restrict__ kws, bf16* __restrict__ vtws) {
  __shared__ __align__(16) bf16 LDS[3 * 24576];

  const int tid = threadIdx.x;
  const int lane = tid & 63, wv = tid >> 6;
  const int q4 = lane >> 4, c = lane & 15;
  const int wm = (wv >> 2) * 64;
  const int wn = (wv & 3) * 64;
  const int cx = c & 7;

  const int bid = blockIdx.x;
  const int wg = (bid & 7) * 96 + (bid >> 3);
  const int m0 = (wg / 24) * 128;
  const int n0 = (wg % 24) * 256;

  f32x4 acc[4][4];
#pragma unroll
  for (int i = 0; i < 4; ++i)
#pragma unroll
    for (int j = 0; j < 4; ++j) acc[i][j] = {0.f, 0.f, 0.f, 0.f};

  const int NT = Eq / 64;

  auto stage = [&](int t, int st) {
    bf16* ab = LDS + st * 24576;
    bf16* bb = ab + 8192;
    const int k0 = t * 64;
#pragma unroll
    for (int it = 0; it < 2; ++it) {
      const int slot = it * 512 + tid;
      const int row = slot >> 3, kch = slot & 7;
      const int kcs = kch ^ (row & 7);
      GLOAD_LDS16(xb + (size_t)(m0 + row) * Eq + k0 + kcs * 8, ab + slot * 8);
    }
#pragma unroll
    for (int it = 0; it < 4; ++it) {
      const int slot = it * 512 + tid;
      const int row = slot >> 3, kch = slot & 7;
      const int kcs = kch ^ (row & 7);
      GLOAD_LDS16(wt + (size_t)(n0 + row) * Eq + k0 + kcs * 8, bb + slot * 8);
    }
  };

  stage(0, 0);
  stage(1, 1);
  asm volatile("s_waitcnt vmcnt(6)" ::: "memory");
  __builtin_amdgcn_s_barrier();

  int stC = 0;
#pragma unroll 1
  for (int t = 0; t < NT; ++t) {
    if (t + 2 < NT) {
      int ss = stC + 2;
      if (ss >= 3) ss -= 3;
      stage(t + 2, ss);
    }
    const bf16* A = LDS + stC * 24576;
    const bf16* Bb = A + 8192;
#pragma unroll
    for (int kk = 0; kk < 64; kk += 32) {
      const int bch = kk >> 3;
      bf16x8 af[4], bfr[4];
#pragma unroll
      for (int i = 0; i < 4; ++i)
        af[i] = *(const bf16x8*)
            &A[(wm + i * 16 + c) * 64 + ((bch + q4) ^ cx) * 8];
#pragma unroll
      for (int j = 0; j < 4; ++j)
        bfr[j] = *(const bf16x8*)
            &Bb[(wn + j * 16 + c) * 64 + ((bch + q4) ^ cx) * 8];
      __builtin_amdgcn_s_setprio(1);
#pragma unroll
      for (int i = 0; i < 4; ++i)
#pragma unroll
        for (int j = 0; j < 4; ++j)
          acc[i][j] = MFMA16(af[i], bfr[j], acc[i][j]);
      __builtin_amdgcn_s_setprio(0);
    }
    if (t + 1 < NT) {
      if (t + 2 < NT) asm volatile("s_waitcnt vmcnt(6)" ::: "memory");
      else            asm volatile("s_waitcnt vmcnt(0)" ::: "memory");
      __builtin_amdgcn_s_barrier();
    }
    stC = stC == 2 ? 0 : stC + 1;
  }
  __syncthreads();

  const int t3 = n0 >> 11;
  const int b = m0 >> 11;
  const int s0 = m0 & 2047;
  const int h0 = (n0 & 2047) >> 7;

  bf16* E = LDS;

  if (t3 == 2) {
#pragma unroll 1
    for (int hh = 0; hh < 2; ++hh) {
      if (((wv & 3) >> 1) == hh) {
#pragma unroll
        for (int i = 0; i < 4; ++i)
#pragma unroll
          for (int j = 0; j < 4; ++j) {
            bf16x4 pv;
            pv[0] = f2bf(acc[i][j][0]); pv[1] = f2bf(acc[i][j][1]);
            pv[2] = f2bf(acc[i][j][2]); pv[3] = f2bf(acc[i][j][3]);
            *(bf16x4*)&E[((wn & 127) + j * 16 + c) * 136 + wm + i * 16 +
                         q4 * 4] = pv;
          }
      }
      __syncthreads();
      bf16* vbase = vtws + ((size_t)(b * Hq + h0 + hh) * Dq) * Sq + s0;
#pragma unroll
      for (int p = 0; p < 4; ++p) {
        const int id = p * 512 + tid;
        const int d = id >> 4, ch = id & 15;
        bf16x8 v = *(const bf16x8*)&E[d * 136 + ch * 8];
        *(bf16x8*)&vbase[(size_t)d * Sq + ch * 8] = v;
      }
      __syncthreads();
    }
  } else {
#pragma unroll 1
    for (int hh = 0; hh < 2; ++hh) {
      if (((wv & 3) >> 1) == hh) {
#pragma unroll
        for (int i = 0; i < 4; ++i)
#pragma unroll
          for (int j = 0; j < 4; ++j)
#pragma unroll
            for (int rr = 0; rr < 4; ++rr)
              E[(wm + i * 16 + q4 * 4 + rr) * 136 + (wn & 127) + j * 16 + c] =
                  f2bf(acc[i][j][rr]);
      }
      __syncthreads();
      bf16* hd = ((t3 == 0) ? qws : kws) +
                 ((size_t)(b * Hq + h0 + hh) * Sq + s0) * Dq;
#pragma unroll
      for (int p = 0; p < 2; ++p) {
        const int row = p * 64 + (tid >> 3);
        const int dlow = (tid & 7) * 8;
        const int s = s0 + row;
        bf16x8 lo = *(const bf16x8*)&E[row * 136 + dlow];
        bf16x8 hi = *(const bf16x8*)&E[row * 136 + 64 + dlow];
        const float2* tb = tbl + (size_t)s * 64 + dlow;
        bf16x8 olo, ohi;
#pragma unroll
        for (int e = 0; e < 8; ++e) {
          const float cv = tb[e].x, sv = tb[e].y;
          const float x1 = bf2f(lo[e]), x2 = bf2f(hi[e]);
          olo[e] = f2bf(x1 * cv - x2 * sv);
          ohi[e] = f2bf(x2 * cv + x1 * sv);
        }
        *(bf16x8*)&hd[(size_t)row * Dq + dlow] = olo;
        *(bf16x8*)&hd[(size_t)row * Dq + 64 + dlow] = ohi;
      }
      __syncthreads();
    }
  }
}

#define KSC (0.08838834764831845f * 1.4426950408889634f)

// ---------------------------------------------------------------------------
// R9 static split-K schedule (passed; attn dropped out of top-5): 24 pieces
// per (h,b) packed into 16 blocks, max 21 chunks. ZP permutes for b=1 so
// CU-paired blocks sum to 32-35 chunks. Machinery verified R8/R9.
// ---------------------------------------------------------------------------
__device__ const int dSQT0[16] = {15,15, 7,14,14, 6,13,13,12,12,11,11, 8,10,10, 9};
__device__ const int dSSP0[16] = { 0, 1, 2, 0, 1, 2, 0, 1, 0, 1, 0, 1, 0, 0, 1, 0};
__device__ const int dSQT1[16] = {-1,-1,-1,-1,-1,-1,-1,-1, 0, 1, 2, 3, 5, 8, 4, 9};
__device__ const int dSSP1[16] = { 0, 0, 0, 0, 0, 0, 0, 0, 2, 2, 2, 2, 2, 1, 2, 1};
__device__ const int dZP[16]   = { 9, 2, 1,13,15,12,14,11,10, 0, 8, 7, 5, 3, 6, 4};

__global__ __launch_bounds__(256, 2) void attn_kernel(
    const bf16* __restrict__ qws, const bf16* __restrict__ kws,
    const bf16* __restrict__ vtws, float* __restrict__ out,
    float* __restrict__ opart, float* __restrict__ ml) {
  __shared__ __align__(16) bf16 Kld[2][8192];
  __shared__ __align__(16) bf16 Vld[2][8192];
  __shared__ __align__(16) bf16 Plds[4][16][72];

  const int tid = threadIdx.x, lane = tid & 63, wave = tid >> 6;
  const int q4 = lane >> 4, c = lane & 15;
  const int h = blockIdx.y, b = blockIdx.z;
  const int sidx = (b == 0) ? blockIdx.x : dZP[blockIdx.x];

  const size_t bh = (size_t)(b * Hq + h);
  const bf16* qbase = qws + bh * Sq * Dq;
  const bf16* kbase = kws + bh * Sq * Dq;
  const bf16* vbase = vtws + bh * Dq * Sq;

#pragma unroll 1
  for (int seg = 0; seg < 2; ++seg) {
    const int qt = (seg == 0) ? dSQT0[sidx] : dSQT1[sidx];
    if (qt < 0) break;
    const int sp = (seg == 0) ? dSSP0[sidx] : dSSP1[sidx];
    const bool split = (sp != 2);
    const int c0 = split ? sp * (qt + 1) : 0;
    const int c1 = split ? c0 + (qt + 1) : 2 * qt + 2;
    const int q0 = qt * 128 + wave * 32;

    bf16x8 qf[2][4];
#pragma unroll
    for (int g = 0; g < 2; ++g)
#pragma unroll
      for (int ks = 0; ks < 4; ++ks)
        qf[g][ks] = *(const bf16x8*)
            &qbase[(size_t)(q0 + g * 16 + c) * Dq + ks * 32 + q4 * 8];

    f32x4 Ot[2][8];
    float m_i[2], l_i[2];
#pragma unroll
    for (int g = 0; g < 2; ++g) {
#pragma unroll
      for (int dj = 0; dj < 8; ++dj) Ot[g][dj] = {0.f, 0.f, 0.f, 0.f};
      m_i[g] = -1e30f; l_i[g] = 0.f;
    }

    {
      const int koff0 = c0 * 64;
#pragma unroll
      for (int it = 0; it < 4; ++it) {
        const int slot = it * 256 + tid;
        GLOAD_LDS16(
            kbase + (size_t)(koff0 + (slot & 63)) * Dq + (slot >> 6) * 8,
            &Kld[c0 & 1][slot * 8]);
        GLOAD_LDS16(
            vbase + (size_t)(slot & 127) * Sq + koff0 + (slot >> 7) * 8,
            &Vld[c0 & 1][slot * 8]);
      }
    }
    __syncthreads();

    for (int kb = c0; kb < c1; ++kb) {
      const int buf = kb & 1;
      if (kb + 1 < c1) {
        const int nb = buf ^ 1;
        const int koff = (kb + 1) * 64;
#pragma unroll
        for (int it = 0; it < 4; ++it) {
          const int slot = it * 256 + tid;
          GLOAD_LDS16(
              kbase + (size_t)(koff + (slot & 63)) * Dq + (slot >> 6) * 8,
              &Kld[nb][slot * 8]);
          GLOAD_LDS16(
              vbase + (size_t)(slot & 127) * Sq + koff + (slot >> 7) * 8,
              &Vld[nb][slot * 8]);
        }
      }
      const bool masked = (kb >= 2 * qt);
#pragma unroll
      for (int g = 0; g < 2; ++g) {
        const int qg = q0 + g * 16 + c;
        f32x4 st[4];
#pragma unroll
        for (int j8 = 0; j8 < 4; ++j8) st[j8] = {0.f, 0.f, 0.f, 0.f};
        __builtin_amdgcn_s_setprio(1);
#pragma unroll
        for (int ks = 0; ks < 4; ++ks) {
          const bf16x8 qv = qf[g][ks];
#pragma unroll
          for (int j8 = 0; j8 < 4; ++j8) {
            const bf16x8 kv = *(const bf16x8*)
                &Kld[buf][((ks * 4 + q4) * 64 + j8 * 16 + c) * 8];
            st[j8] = MFMA16(kv, qv, st[j8]);
          }
        }
        __builtin_amdgcn_s_setprio(0);
        if (masked) {
          const int kb64 = kb * 64 + q4 * 4;
#pragma unroll
          for (int j8 = 0; j8 < 4; ++j8)
#pragma unroll
            for (int rr = 0; rr < 4; ++rr)
              if (kb64 + j8 * 16 + rr > qg) st[j8][rr] = -1e30f;
        }
        float mloc = -1e30f;
#pragma unroll
        for (int j8 = 0; j8 < 4; ++j8)
#pragma unroll
          for (int rr = 0; rr < 4; ++rr) mloc = fmaxf(mloc, st[j8][rr]);
        mloc = fmaxf(mloc, __shfl_xor(mloc, 16, 64));
        mloc = fmaxf(mloc, __shfl_xor(mloc, 32, 64));
        float mn = m_i[g];
        if (__any(mloc > mn)) {
          mn = fmaxf(mn, mloc);
          const float alpha = exp2f((m_i[g] - mn) * KSC);
          m_i[g] = mn;
          l_i[g] *= alpha;
#pragma unroll
          for (int dj = 0; dj < 8; ++dj) Ot[g][dj] *= alpha;
        }
        float ssum = 0.f;
#pragma unroll
        for (int j8 = 0; j8 < 4; ++j8)
#pragma unroll
          for (int rr = 0; rr < 4; ++rr) {
            const float p = exp2f((st[j8][rr] - mn) * KSC);
            st[j8][rr] = p;
            ssum += p;
          }
        ssum += __shfl_xor(ssum, 16, 64);
        ssum += __shfl_xor(ssum, 32, 64);
        l_i[g] += ssum;
#pragma unroll
        for (int j8 = 0; j8 < 4; ++j8) {
          bf16x4 pk;
          pk[0] = f2bf(st[j8][0]); pk[1] = f2bf(st[j8][1]);
          pk[2] = f2bf(st[j8][2]); pk[3] = f2bf(st[j8][3]);
          *(bf16x4*)&Plds[wave][c][j8 * 16 + q4 * 4] = pk;
        }
        __builtin_amdgcn_s_setprio(1);
#pragma unroll
        for (int ks = 0; ks < 2; ++ks) {
          const bf16x8 pv = *(const bf16x8*)&Plds[wave][c][ks * 32 + q4 * 8];
#pragma unroll
          for (int dj = 0; dj < 8; ++dj) {
            const bf16x8 vv = *(const bf16x8*)
                &Vld[buf][((ks * 4 + q4) * 128 + dj * 16 + c) * 8];
            Ot[g][dj] = MFMA16(vv, pv, Ot[g][dj]);
          }
        }
        __builtin_amdgcn_s_setprio(0);
      }
      __syncthreads();
    }

    if (!split) {
#pragma unroll
      for (int g = 0; g < 2; ++g) {
        const float inv = 1.0f / l_i[g];
        float* orow = out + ((size_t)b * Sq + q0 + g * 16 + c) * Eq + h * Dq;
#pragma unroll
        for (int dj = 0; dj < 8; ++dj) {
          float4 o;
          o.x = Ot[g][dj][0] * inv; o.y = Ot[g][dj][1] * inv;
          o.z = Ot[g][dj][2] * inv; o.w = Ot[g][dj][3] * inv;
          *(float4*)&orow[dj * 16 + q4 * 4] = o;
        }
      }
    } else {
      const int tix = (((b * Hq + h) * 8) + (qt - 8)) * 2 + sp;
#pragma unroll
      for (int g = 0; g < 2; ++g) {
        const int wrow = wave * 32 + g * 16 + c;
        float* prow = opart + ((size_t)tix * 128 + wrow) * 128;
#pragma unroll
        for (int dj = 0; dj < 8; ++dj) {
          float4 o;
          o.x = Ot[g][dj][0]; o.y = Ot[g][dj][1];
          o.z = Ot[g][dj][2]; o.w = Ot[g][dj][3];
          *(float4*)&prow[dj * 16 + q4 * 4] = o;
        }
        if (q4 == 0) {
          ml[((size_t)tix * 128 + wrow) * 2 + 0] = m_i[g];
          ml[((size_t)tix * 128 + wrow) * 2 + 1] = l_i[g];
        }
      }
    }
  }
}

// ---------------------------------------------------------------------------
// Kernel 4: combine the two split-K halves for qt>=8 tiles (R8/R9-verified).
// ---------------------------------------------------------------------------
__global__ __launch_bounds__(256) void attn_combine(
    const float* __restrict__ opart, const float* __restrict__ ml,
    float* __restrict__ out) {
  const int tile = blockIdx.x;
  const int qt = (tile & 7) + 8;
  const int hb = tile >> 3;
  const int h = hb & 15, b = hb >> 4;
  const int tid = threadIdx.x;
  const int r = tid >> 1;
  const int d0 = (tid & 1) * 64;
  const int t0 = tile * 2, t1 = t0 + 1;

  const float m0 = ml[((size_t)t0 * 128 + r) * 2 + 0];
  const float l0 = ml[((size_t)t0 * 128 + r) * 2 + 1];
  const float m1 = ml[((size_t)t1 * 128 + r) * 2 + 0];
  const float l1 = ml[((size_t)t1 * 128 + r) * 2 + 1];
  const float m = fmaxf(m0, m1);
  const float w0 = exp2f((m0 - m) * KSC);
  const float w1 = exp2f((m1 - m) * KSC);
  const float inv = 1.0f / (l0 * w0 + l1 * w1);
  const float s0 = w0 * inv, s1 = w1 * inv;

  const float* p0 = opart + ((size_t)t0 * 128 + r) * 128 + d0;
  const float* p1 = opart + ((size_t)t1 * 128 + r) * 128 + d0;
  float* orow = out + ((size_t)(b * Sq + qt * 128 + r)) * Eq + h * Dq + d0;
#pragma unroll
  for (int i = 0; i < 16; ++i) {
    float4 a = *(const float4*)&p0[i * 4];
    float4 bb = *(const float4*)&p1[i * 4];
    float4 o;
    o.x = a.x * s0 + bb.x * s1;
    o.y = a.y * s0 + bb.y * s1;
    o.z = a.z * s0 + bb.z * s1;
    o.w = a.w * s0 + bb.w * s1;
    *(float4*)&orow[i * 4] = o;
  }
}

// ---------------------------------------------------------------------------
extern "C" void kernel_launch(void* const* d_in, const int* in_sizes, int n_in,
                              void* d_out, int out_size, void* d_ws,
                              size_t ws_size, hipStream_t stream) {
  const float* x = (const float*)d_in[0];
  // d_in[1] = mask (causal tril) — implemented analytically, not read.
  const float* w = (const float*)d_in[2];
  float* out = (float*)d_out;

  const size_t nX = (size_t)Bq * Sq * Eq;         // 8,388,608
  const size_t nW = (size_t)Eq * N3E;             // 12,582,912
  const size_t perT = (size_t)Bq * Hq * Sq * Dq;  // 8,388,608

  bf16* xb = (bf16*)d_ws;
  bf16* wt = xb + nX;
  bf16* qws = wt + nW;
  bf16* kws = qws + perT;
  bf16* vtws = kws + perT;
  float2* tbl = (float2*)(vtws + perT);  // 2048*64 float2 = 1 MB
  float* wsend = (float*)(tbl + (size_t)Sq * 64);

  // Split-K partials: R9 aliased them over xb/wt, which cost gemm +11 us
  // (FETCH 313->367 MB: dirty opart lines over gemm's input addresses
  // between iterations). Place in a DEDICATED region after tbl when the
  // workspace allows; fall back to the R9 aliasing otherwise.
  const size_t nOpart = (size_t)512 * 128 * 128;      // 33.55 MB f32
  const size_t nMl = (size_t)512 * 128 * 2;           // 0.5 MB f32
  const size_t usedB = (size_t)((char*)wsend - (char*)d_ws);
  float* opart;
  if (ws_size >= usedB + (nOpart + nMl) * sizeof(float)) {
    opart = wsend;               // dedicated region (no aliasing)
  } else {
    opart = (float*)d_ws;        // R9 fallback
  }
  float* ml = opart + nOpart;

  prep<<<7680, 256, 0, stream>>>(x, xb, w, wt, tbl);

  gemm_qkv<<<768, 512, 0, stream>>>(xb, wt, tbl, qws, kws, vtws);

  dim3 g3(16, 16, 2);  // 512 blocks = resident-slot count; static schedule
  attn_kernel<<<g3, 256, 0, stream>>>(qws, kws, vtws, out, opart, ml);

  attn_combine<<<256, 256, 0, stream>>>(opart, ml, out);
}